// Round 9
// baseline (379.053 us; speedup 1.0000x reference)
//
#include <hip/hip_runtime.h>
#include <hip/hip_cooperative_groups.h>

namespace cg = cooperative_groups;

// B=4, T=2048, C=1024, H=64. fp32 in/out, bf16 MFMA internally.
// One kernel, three phases (wtrans -> proj -> attn), each grid-stride.
// phase_mask: 7 = all phases in one cooperative launch (grid syncs between);
// 1/2/4 = single phase per ordinary launch (kernel boundary = coherence).
// ws layout (u16 elements):
//   [0,        524288)  q  bf16 (PRE-SCALED by 1/8)  [b*2048+t][64]
//   [524288,  1048576)  k  bf16  [b*2048+t][64]
//   [1048576, 1572864)  vT bf16  [b][h][t]   (b*131072 + h*2048 + t)
//   [1572864, 1769472)  wT bf16  [sel][h][c] (sel*65536 + h*1024 + c)

typedef __attribute__((ext_vector_type(8))) short short8;
typedef __attribute__((ext_vector_type(4))) float f32x4;

#define NTOT 524288   // 8192*64
#define WT_OFF (3 * NTOT)

__device__ __forceinline__ unsigned short f2bf(float f) {
    unsigned int u = __builtin_bit_cast(unsigned int, f);
    return (unsigned short)((u + 0x7fffu + ((u >> 16) & 1u)) >> 16);
}

__device__ __forceinline__ short8 pack8(float4 a, float4 b) {
    short8 r;
    r[0] = (short)f2bf(a.x); r[1] = (short)f2bf(a.y);
    r[2] = (short)f2bf(a.z); r[3] = (short)f2bf(a.w);
    r[4] = (short)f2bf(b.x); r[5] = (short)f2bf(b.y);
    r[6] = (short)f2bf(b.z); r[7] = (short)f2bf(b.w);
    return r;
}

__global__ __launch_bounds__(512, 4) void fused_kernel(
    const float* __restrict__ x, const float* __restrict__ Wq,
    const float* __restrict__ Wk, const float* __restrict__ Wv,
    unsigned short* __restrict__ ws, float* __restrict__ out,
    int phase_mask)
{
    __shared__ float smem[13568];   // 54,272 B arena, reused per phase
    const int tid = threadIdx.x;
    const int bid = blockIdx.x;
    const int nb  = gridDim.x;
    const int wave = tid >> 6, lane = tid & 63;
    const int quad = lane >> 4, l16 = lane & 15;
    unsigned short* wt = ws + WT_OFF;

    // ================= Phase 0: W transpose (48 jobs) =================
    if (phase_mask & 1) {
        for (int job = bid; job < 48; job += nb) {
            __syncthreads();
            const int sel = job % 3;
            const int c0  = (job / 3) * 64;
            const float* W = (sel == 0) ? Wq : ((sel == 1) ? Wk : Wv);
            unsigned short* tile = (unsigned short*)smem;   // [64][72]
            {
                const int c  = tid >> 3;          // 0..63
                const int hg = (tid & 7) * 8;
                const float* src = W + (size_t)(c0 + c) * 64 + hg;
                #pragma unroll
                for (int i = 0; i < 8; i++) tile[c * 72 + hg + i] = f2bf(src[i]);
            }
            __syncthreads();
            {
                const int h  = tid >> 3;
                const int cg = (tid & 7) * 8;
                unsigned short* dst = wt + ((size_t)sel * 64 + h) * 1024 + c0 + cg;
                #pragma unroll
                for (int i = 0; i < 8; i++) dst[i] = tile[(cg + i) * 72 + h];
            }
        }
    }
    if (phase_mask == 7) { __threadfence(); cg::this_grid().sync(); __threadfence(); }

    // ================= Phase 1: projections (16 rows / job) =================
    if (phase_mask & 2) {
        const unsigned short* wq = wt;
        const unsigned short* wk = wt + 65536;
        const unsigned short* wv = wt + 131072;
        for (int m0 = bid * 16; m0 < 8192; m0 += nb * 16) {
            __syncthreads();
            f32x4 aq[4] = {}, ak[4] = {}, av[4] = {};
            const int kbase = wave * 128;
            const float* xrow = x + (size_t)(m0 + l16) * 1024 + kbase + quad * 8;
            float4 xa = *(const float4*)(xrow);
            float4 xb = *(const float4*)(xrow + 4);
            #pragma unroll
            for (int kk = 0; kk < 128; kk += 32) {
                const int nk = (kk + 32) & 127;   // wraps on last iter (unused)
                float4 na = *(const float4*)(xrow + nk);
                float4 nb2 = *(const float4*)(xrow + nk + 4);
                short8 af = pack8(xa, xb);
                const int wo = kbase + kk + quad * 8;
                #pragma unroll
                for (int nt = 0; nt < 4; nt++) {
                    const size_t ro = (size_t)(nt * 16 + l16) * 1024 + wo;
                    short8 bq = *(const short8*)(wq + ro);
                    short8 bk = *(const short8*)(wk + ro);
                    short8 bv = *(const short8*)(wv + ro);
                    aq[nt] = __builtin_amdgcn_mfma_f32_16x16x32_bf16(af, bq, aq[nt], 0, 0, 0);
                    ak[nt] = __builtin_amdgcn_mfma_f32_16x16x32_bf16(af, bk, ak[nt], 0, 0, 0);
                    av[nt] = __builtin_amdgcn_mfma_f32_16x16x32_bf16(bv, af, av[nt], 0, 0, 0);
                }
                xa = na; xb = nb2;
            }
            const int b   = m0 >> 11;
            const int tb0 = m0 & 2047;
            const int rrow = tid >> 5, rh0 = (tid & 31) * 2;
            // ---- stage Q (pre-scaled by 1/8: exact) ----
            #pragma unroll
            for (int nt = 0; nt < 4; nt++)
                #pragma unroll
                for (int r = 0; r < 4; r++)
                    smem[(wave * 16 + quad * 4 + r) * 66 + nt * 16 + l16] = aq[nt][r];
            __syncthreads();
            #pragma unroll
            for (int i = 0; i < 2; i++) {
                const int h = rh0 + i;
                float s = 0.f;
                #pragma unroll
                for (int w = 0; w < 8; w++) s += smem[(w * 16 + rrow) * 66 + h];
                ws[(size_t)(m0 + rrow) * 64 + h] = f2bf(s * 0.125f);
            }
            __syncthreads();
            // ---- stage K ----
            #pragma unroll
            for (int nt = 0; nt < 4; nt++)
                #pragma unroll
                for (int r = 0; r < 4; r++)
                    smem[(wave * 16 + quad * 4 + r) * 66 + nt * 16 + l16] = ak[nt][r];
            __syncthreads();
            #pragma unroll
            for (int i = 0; i < 2; i++) {
                const int h = rh0 + i;
                float s = 0.f;
                #pragma unroll
                for (int w = 0; w < 8; w++) s += smem[(w * 16 + rrow) * 66 + h];
                ws[NTOT + (size_t)(m0 + rrow) * 64 + h] = f2bf(s);
            }
            __syncthreads();
            // ---- stage V: h = nt*16+quad*4+r, t = l16 ----
            #pragma unroll
            for (int nt = 0; nt < 4; nt++)
                #pragma unroll
                for (int r = 0; r < 4; r++)
                    smem[(wave * 64 + nt * 16 + quad * 4 + r) * 17 + l16] = av[nt][r];
            __syncthreads();
            {
                const int h = tid >> 3, t0 = (tid & 7) * 2;
                unsigned short* vdst = ws + 2 * NTOT + (size_t)b * 131072
                                     + (size_t)h * 2048 + tb0;
                #pragma unroll
                for (int i = 0; i < 2; i++) {
                    const int t = t0 + i;
                    float s = 0.f;
                    #pragma unroll
                    for (int w = 0; w < 8; w++) s += smem[(w * 64 + h) * 17 + t];
                    vdst[t] = f2bf(s);
                }
            }
        }
    }
    if (phase_mask == 7) { __threadfence(); cg::this_grid().sync(); __threadfence(); }

    // ================= Phase 2: flash attention (512 jobs) =================
    if (phase_mask & 4) {
        unsigned short* p_lds = (unsigned short*)smem;  // [8][16][72] u16
        float* o_red  = smem + 4608;                    // [8][16][68] f32
        float* ml_red = smem + 13312;                   // [8][2][16]  f32
        for (int Bi = bid; Bi < 512; Bi += nb) {
            __syncthreads();
            const int xcd  = Bi & 7;
            const int slot = Bi >> 3;
            const int b    = xcd & 3;
            const int qt   = (slot << 1) | (xcd >> 2);   // 0..127
            const int q0   = qt * 16;

            const unsigned short* Q  = ws + (size_t)b * 131072;
            const unsigned short* K  = ws + NTOT + (size_t)b * 131072;
            const unsigned short* VT = ws + 2 * NTOT + (size_t)b * 131072;

            const int qrow = q0 + l16;
            short8 qf0 = *(const short8*)(Q + (size_t)qrow * 64 + quad * 8);
            short8 qf1 = *(const short8*)(Q + (size_t)qrow * 64 + 32 + quad * 8);

            f32x4 o[4] = {};
            float m_i[4], l_i[4];
            #pragma unroll
            for (int r = 0; r < 4; r++) { m_i[r] = -1e30f; l_i[r] = 0.f; }

            const int qi = q0 + quad * 4;
            const int nkt = (qt >> 2) + 1;

            for (int t = wave; t < nkt; t += 8) {
                const int j0 = t * 64;
                f32x4 s[4] = {};
                #pragma unroll
                for (int nt = 0; nt < 4; nt++) {
                    const unsigned short* kp = K + (size_t)(j0 + nt * 16 + l16) * 64 + quad * 8;
                    short8 kf0 = *(const short8*)(kp);
                    short8 kf1 = *(const short8*)(kp + 32);
                    s[nt] = __builtin_amdgcn_mfma_f32_16x16x32_bf16(qf0, kf0, s[nt], 0, 0, 0);
                    s[nt] = __builtin_amdgcn_mfma_f32_16x16x32_bf16(qf1, kf1, s[nt], 0, 0, 0);
                }
                float pm[4] = {-1e30f, -1e30f, -1e30f, -1e30f};
                #pragma unroll
                for (int nt = 0; nt < 4; nt++) {
                    const int kj = j0 + nt * 16 + l16;
                    #pragma unroll
                    for (int r = 0; r < 4; r++) {
                        float v = s[nt][r];   // scale folded into q
                        v = (kj > qi + r || v == 0.0f) ? -1e30f : v;
                        s[nt][r] = v;
                        pm[r] = fmaxf(pm[r], v);
                    }
                }
                #pragma unroll
                for (int off = 1; off < 16; off <<= 1)
                    #pragma unroll
                    for (int r = 0; r < 4; r++)
                        pm[r] = fmaxf(pm[r], __shfl_xor(pm[r], off));
                float alpha[4];
                #pragma unroll
                for (int r = 0; r < 4; r++) {
                    float mn = fmaxf(m_i[r], pm[r]);
                    alpha[r] = __expf(m_i[r] - mn);
                    m_i[r] = mn;
                }
                float ps[4] = {0.f, 0.f, 0.f, 0.f};
                #pragma unroll
                for (int nt = 0; nt < 4; nt++)
                    #pragma unroll
                    for (int r = 0; r < 4; r++) {
                        float p = __expf(s[nt][r] - m_i[r]);
                        ps[r] += p;
                        p_lds[(wave * 16 + quad * 4 + r) * 72 + nt * 16 + l16] = f2bf(p);
                    }
                #pragma unroll
                for (int off = 1; off < 16; off <<= 1)
                    #pragma unroll
                    for (int r = 0; r < 4; r++)
                        ps[r] += __shfl_xor(ps[r], off);
                #pragma unroll
                for (int r = 0; r < 4; r++) l_i[r] = l_i[r] * alpha[r] + ps[r];
                #pragma unroll
                for (int ht = 0; ht < 4; ht++)
                    #pragma unroll
                    for (int r = 0; r < 4; r++)
                        o[ht][r] *= alpha[r];
                #pragma unroll
                for (int ks = 0; ks < 2; ks++) {
                    short8 pf = *(const short8*)&p_lds[(wave * 16 + l16) * 72 + ks * 32 + quad * 8];
                    #pragma unroll
                    for (int ht = 0; ht < 4; ht++) {
                        short8 vf = *(const short8*)(VT + (size_t)(ht * 16 + l16) * 2048 + j0 + ks * 32 + quad * 8);
                        o[ht] = __builtin_amdgcn_mfma_f32_16x16x32_bf16(pf, vf, o[ht], 0, 0, 0);
                    }
                }
            }

            #pragma unroll
            for (int ht = 0; ht < 4; ht++)
                #pragma unroll
                for (int r = 0; r < 4; r++)
                    o_red[(wave * 16 + quad * 4 + r) * 68 + ht * 16 + l16] = o[ht][r];
            if (l16 == 0) {
                #pragma unroll
                for (int r = 0; r < 4; r++) {
                    ml_red[wave * 32 + quad * 4 + r]      = m_i[r];
                    ml_red[wave * 32 + 16 + quad * 4 + r] = l_i[r];
                }
            }
            __syncthreads();

            const int row = tid >> 5, c0 = (tid & 31) * 2;
            float M = -1e30f;
            #pragma unroll
            for (int w = 0; w < 8; w++) M = fmaxf(M, ml_red[w * 32 + row]);
            float wgt[8];
            float l = 0.f;
            #pragma unroll
            for (int w = 0; w < 8; w++) {
                wgt[w] = __expf(ml_red[w * 32 + row] - M);
                l += wgt[w] * ml_red[w * 32 + 16 + row];
            }
            const float inv = 1.0f / l;
            float* op = out + ((size_t)b * 2048 + q0 + row) * 64 + c0;
            #pragma unroll
            for (int i = 0; i < 2; i++) {
                const int col = c0 + i;
                float sv = 0.f;
                #pragma unroll
                for (int w = 0; w < 8; w++) sv += wgt[w] * o_red[(w * 16 + row) * 68 + col];
                op[i] = sv * inv;
            }
        }
    }
}

// ---------------------------------------------------------------------------
extern "C" void kernel_launch(void* const* d_in, const int* in_sizes, int n_in,
                              void* d_out, int out_size, void* d_ws, size_t ws_size,
                              hipStream_t stream) {
    const float* x  = (const float*)d_in[0];
    const float* Wq = (const float*)d_in[1];
    const float* Wk = (const float*)d_in[2];
    const float* Wv = (const float*)d_in[3];
    float* out = (float*)d_out;
    unsigned short* ws = (unsigned short*)d_ws;

    // Try single cooperative launch sized to ACTUAL occupancy; verify rc.
    int occ = 0;
    hipError_t oe = hipOccupancyMaxActiveBlocksPerMultiprocessor(
        &occ, (const void*)fused_kernel, 512, 0);
    bool done = false;
    if (oe == hipSuccess && occ > 0) {
        int nb = occ * 256;
        if (nb > 512) nb = 512;
        int mask = 7;
        void* args[7] = {(void*)&x, (void*)&Wq, (void*)&Wk, (void*)&Wv,
                         (void*)&ws, (void*)&out, (void*)&mask};
        if (hipLaunchCooperativeKernel((const void*)fused_kernel, dim3(nb),
                                       dim3(512), args, 0, stream) == hipSuccess)
            done = true;
    }
    if (!done) {
        // Fallback: three ordinary launches (kernel boundary = coherence).
        fused_kernel<<<dim3(512), dim3(512), 0, stream>>>(x, Wq, Wk, Wv, ws, out, 1);
        fused_kernel<<<dim3(512), dim3(512), 0, stream>>>(x, Wq, Wk, Wv, ws, out, 2);
        fused_kernel<<<dim3(512), dim3(512), 0, stream>>>(x, Wq, Wk, Wv, ws, out, 4);
    }
}

// Round 10
// 126.094 us; speedup vs baseline: 3.0061x; 3.0061x over previous
//
#include <hip/hip_runtime.h>

// B=4, T=2048, C=1024, H=64. fp32 in/out, bf16 MFMA internally.
// Three ordinary dispatches (kernel boundary = cross-XCD coherence):
//   wtrans -> proj (q pre-scaled by 1/8) -> attn (two-pass softmax, S^T).
// ws layout (u16 elements):
//   [0,        524288)  q  bf16 (PRE-SCALED by 1/8)  [b*2048+t][64]
//   [524288,  1048576)  k  bf16  [b*2048+t][64]
//   [1048576, 1572864)  vT bf16  [b][h][t]   (b*131072 + h*2048 + t)
//   [1572864, 1769472)  wT bf16  [sel][h][c] (sel*65536 + h*1024 + c)

typedef __attribute__((ext_vector_type(8))) short short8;
typedef __attribute__((ext_vector_type(4))) float f32x4;

#define NTOT 524288   // 8192*64
#define WT_OFF (3 * NTOT)

__device__ __forceinline__ unsigned short f2bf(float f) {
    unsigned int u = __builtin_bit_cast(unsigned int, f);
    return (unsigned short)((u + 0x7fffu + ((u >> 16) & 1u)) >> 16);
}

__device__ __forceinline__ short8 pack8(float4 a, float4 b) {
    short8 r;
    r[0] = (short)f2bf(a.x); r[1] = (short)f2bf(a.y);
    r[2] = (short)f2bf(a.z); r[3] = (short)f2bf(a.w);
    r[4] = (short)f2bf(b.x); r[5] = (short)f2bf(b.y);
    r[6] = (short)f2bf(b.z); r[7] = (short)f2bf(b.w);
    return r;
}

// ---------------------------------------------------------------------------
// Kernel 1: W transpose (proven r9 phase-0 body). 48 blocks x 512.
// ---------------------------------------------------------------------------
__global__ __launch_bounds__(512) void wtrans_kernel(
    const float* __restrict__ Wq, const float* __restrict__ Wk,
    const float* __restrict__ Wv, unsigned short* __restrict__ wt)
{
    __shared__ unsigned short tile[64 * 72];
    const int tid = threadIdx.x;
    const int sel = blockIdx.x % 3;
    const int c0  = (blockIdx.x / 3) * 64;
    const float* W = (sel == 0) ? Wq : ((sel == 1) ? Wk : Wv);
    {
        const int c  = tid >> 3;          // 0..63
        const int hg = (tid & 7) * 8;
        const float* src = W + (size_t)(c0 + c) * 64 + hg;
        #pragma unroll
        for (int i = 0; i < 8; i++) tile[c * 72 + hg + i] = f2bf(src[i]);
    }
    __syncthreads();
    {
        const int h  = tid >> 3;
        const int cg = (tid & 7) * 8;
        unsigned short* dst = wt + ((size_t)sel * 64 + h) * 1024 + c0 + cg;
        #pragma unroll
        for (int i = 0; i < 8; i++) dst[i] = tile[(cg + i) * 72 + h];
    }
}

// ---------------------------------------------------------------------------
// Kernel 2: fused projections (proven r9 phase-1 body). 512 blocks x 512.
// Block -> 16 t-rows; wave w -> K in [w*128,(w+1)*128): 4 iters.
// 8-way LDS reduce in 3 stages; q stored pre-scaled by 1/8.
// ---------------------------------------------------------------------------
__global__ __launch_bounds__(512, 4) void proj_kernel(
    const float* __restrict__ x, const unsigned short* __restrict__ wt,
    unsigned short* __restrict__ ws)
{
    __shared__ float smem[8 * 16 * 66 + 256];
    const int tid = threadIdx.x;
    const int wave = tid >> 6, lane = tid & 63;
    const int quad = lane >> 4, l16 = lane & 15;
    const int m0 = blockIdx.x * 16;
    const unsigned short* wq = ws + WT_OFF;
    const unsigned short* wk = wq + 65536;
    const unsigned short* wv = wq + 131072;

    f32x4 aq[4] = {}, ak[4] = {}, av[4] = {};
    const int kbase = wave * 128;
    const float* xrow = x + (size_t)(m0 + l16) * 1024 + kbase + quad * 8;
    float4 xa = *(const float4*)(xrow);
    float4 xb = *(const float4*)(xrow + 4);
    #pragma unroll
    for (int kk = 0; kk < 128; kk += 32) {
        const int nk = (kk + 32) & 127;   // wraps on last iter (unused)
        float4 na  = *(const float4*)(xrow + nk);
        float4 nb2 = *(const float4*)(xrow + nk + 4);
        short8 af = pack8(xa, xb);
        const int wo = kbase + kk + quad * 8;
        #pragma unroll
        for (int nt = 0; nt < 4; nt++) {
            const size_t ro = (size_t)(nt * 16 + l16) * 1024 + wo;
            short8 bq = *(const short8*)(wq + ro);
            short8 bk = *(const short8*)(wk + ro);
            short8 bv = *(const short8*)(wv + ro);
            aq[nt] = __builtin_amdgcn_mfma_f32_16x16x32_bf16(af, bq, aq[nt], 0, 0, 0);
            ak[nt] = __builtin_amdgcn_mfma_f32_16x16x32_bf16(af, bk, ak[nt], 0, 0, 0);
            av[nt] = __builtin_amdgcn_mfma_f32_16x16x32_bf16(bv, af, av[nt], 0, 0, 0);
        }
        xa = na; xb = nb2;
    }
    const int b   = m0 >> 11;
    const int tb0 = m0 & 2047;
    const int rrow = tid >> 5, rh0 = (tid & 31) * 2;
    // ---- stage Q (pre-scale 1/8, exact) ----
    #pragma unroll
    for (int nt = 0; nt < 4; nt++)
        #pragma unroll
        for (int r = 0; r < 4; r++)
            smem[(wave * 16 + quad * 4 + r) * 66 + nt * 16 + l16] = aq[nt][r];
    __syncthreads();
    #pragma unroll
    for (int i = 0; i < 2; i++) {
        const int h = rh0 + i;
        float s = 0.f;
        #pragma unroll
        for (int w = 0; w < 8; w++) s += smem[(w * 16 + rrow) * 66 + h];
        ws[(size_t)(m0 + rrow) * 64 + h] = f2bf(s * 0.125f);
    }
    __syncthreads();
    // ---- stage K ----
    #pragma unroll
    for (int nt = 0; nt < 4; nt++)
        #pragma unroll
        for (int r = 0; r < 4; r++)
            smem[(wave * 16 + quad * 4 + r) * 66 + nt * 16 + l16] = ak[nt][r];
    __syncthreads();
    #pragma unroll
    for (int i = 0; i < 2; i++) {
        const int h = rh0 + i;
        float s = 0.f;
        #pragma unroll
        for (int w = 0; w < 8; w++) s += smem[(w * 16 + rrow) * 66 + h];
        ws[NTOT + (size_t)(m0 + rrow) * 64 + h] = f2bf(s);
    }
    __syncthreads();
    // ---- stage V: h = nt*16+quad*4+r, t = l16 ----
    #pragma unroll
    for (int nt = 0; nt < 4; nt++)
        #pragma unroll
        for (int r = 0; r < 4; r++)
            smem[(wave * 64 + nt * 16 + quad * 4 + r) * 17 + l16] = av[nt][r];
    __syncthreads();
    {
        const int h = tid >> 3, t0 = (tid & 7) * 2;
        unsigned short* vdst = ws + 2 * NTOT + (size_t)b * 131072
                             + (size_t)h * 2048 + tb0;
        #pragma unroll
        for (int i = 0; i < 2; i++) {
            const int t = t0 + i;
            float s = 0.f;
            #pragma unroll
            for (int w = 0; w < 8; w++) s += smem[(w * 64 + h) * 17 + t];
            vdst[t] = f2bf(s);
        }
    }
}

// ---------------------------------------------------------------------------
// Kernel 3: flash attention, TWO-PASS per-wave softmax via S^T.
// 512 blocks x 512 thr (8 waves); block = 16 q-rows; wave w owns k-tiles
// t = w, w+8, ... (<=4). Pass A: S^T = K.Q^T for all owned tiles into regs
// (lane's 16 values share q = lane&15 -> in-register row reduce + 2
// shuffles). Pass B: exp (no online rescale), P->LDS, O += P.V^T.
// Cross-wave combine via LDS. XCD swizzle: xcd=bid&7 serves one batch.
// ---------------------------------------------------------------------------
__global__ __launch_bounds__(512, 2) void attn_kernel(
    const unsigned short* __restrict__ ws, float* __restrict__ out)
{
    __shared__ unsigned short p_lds[8 * 16 * 72];   // 18.4 KB
    __shared__ float o_red[8 * 16 * 68];            // 34.8 KB
    __shared__ float ml_red[8 * 32];                // 1 KB
    const int tid = threadIdx.x;
    const int bid = blockIdx.x;
    const int wave = tid >> 6, lane = tid & 63;
    const int quad = lane >> 4, l16 = lane & 15;

    const int xcd  = bid & 7;
    const int slot = bid >> 3;
    const int b    = xcd & 3;
    const int qt   = (slot << 1) | (xcd >> 2);   // 0..127
    const int q0   = qt * 16;

    const unsigned short* Q  = ws + (size_t)b * 131072;
    const unsigned short* K  = ws + NTOT + (size_t)b * 131072;
    const unsigned short* VT = ws + 2 * NTOT + (size_t)b * 131072;

    // Q fragments (B-operand): B[k=c][n=l16] = Q[q0+l16][c]
    const int qrow = q0 + l16;
    short8 qf0 = *(const short8*)(Q + (size_t)qrow * 64 + quad * 8);
    short8 qf1 = *(const short8*)(Q + (size_t)qrow * 64 + 32 + quad * 8);

    const int nkt = (qt >> 2) + 1;       // k-tiles for this q-tile
    const int qi  = q0 + l16;            // this lane's q row

    // ---- Pass A: S^T for up to 4 owned tiles (independent -> ILP) ----
    f32x4 st[4][4] = {};
    #pragma unroll
    for (int ti = 0; ti < 4; ti++) {
        const int t = wave + ti * 8;
        if (t < nkt) {
            const int j0 = t * 64;
            #pragma unroll
            for (int nt = 0; nt < 4; nt++) {
                const unsigned short* kp = K + (size_t)(j0 + nt * 16 + l16) * 64 + quad * 8;
                short8 kf0 = *(const short8*)(kp);
                short8 kf1 = *(const short8*)(kp + 32);
                st[ti][nt] = __builtin_amdgcn_mfma_f32_16x16x32_bf16(kf0, qf0, st[ti][nt], 0, 0, 0);
                st[ti][nt] = __builtin_amdgcn_mfma_f32_16x16x32_bf16(kf1, qf1, st[ti][nt], 0, 0, 0);
            }
        }
    }
    // ---- mask (causal + ==0 quirk; scale pre-folded into q) + reg max ----
    float mx = -1e30f;
    #pragma unroll
    for (int ti = 0; ti < 4; ti++) {
        const int t = wave + ti * 8;
        if (t < nkt) {
            const int j0 = t * 64;
            #pragma unroll
            for (int nt = 0; nt < 4; nt++) {
                const int kb = j0 + nt * 16 + quad * 4;
                #pragma unroll
                for (int r = 0; r < 4; r++) {
                    float v = st[ti][nt][r];
                    v = (kb + r > qi || v == 0.0f) ? -1e30f : v;
                    st[ti][nt][r] = v;
                    mx = fmaxf(mx, v);
                }
            }
        }
    }
    // cross-quad max (lanes l16, l16+16, l16+32, l16+48 share q)
    mx = fmaxf(mx, __shfl_xor(mx, 16));
    mx = fmaxf(mx, __shfl_xor(mx, 32));

    // ---- Pass B: exp, P->LDS, O += P.V^T (no rescaling needed) ----
    float lsum = 0.f;
    f32x4 o[4] = {};
    #pragma unroll
    for (int ti = 0; ti < 4; ti++) {
        const int t = wave + ti * 8;
        if (t < nkt) {
            const int j0 = t * 64;
            #pragma unroll
            for (int nt = 0; nt < 4; nt++)
                #pragma unroll
                for (int r = 0; r < 4; r++) {
                    float p = __expf(st[ti][nt][r] - mx);
                    lsum += p;
                    // P[q=l16][k_local = nt*16 + quad*4 + r]
                    p_lds[(wave * 16 + l16) * 72 + nt * 16 + quad * 4 + r] = f2bf(p);
                }
            #pragma unroll
            for (int ks = 0; ks < 2; ks++) {
                short8 pf = *(const short8*)&p_lds[(wave * 16 + l16) * 72 + ks * 32 + quad * 8];
                #pragma unroll
                for (int ht = 0; ht < 4; ht++) {
                    short8 vf = *(const short8*)(VT + (size_t)(ht * 16 + l16) * 2048 + j0 + ks * 32 + quad * 8);
                    o[ht] = __builtin_amdgcn_mfma_f32_16x16x32_bf16(pf, vf, o[ht], 0, 0, 0);
                }
            }
        }
    }
    lsum += __shfl_xor(lsum, 16);
    lsum += __shfl_xor(lsum, 32);

    // ---- stash per-wave partial state (O: q=quad*4+r space; m/l: q=l16) ----
    #pragma unroll
    for (int ht = 0; ht < 4; ht++)
        #pragma unroll
        for (int r = 0; r < 4; r++)
            o_red[(wave * 16 + quad * 4 + r) * 68 + ht * 16 + l16] = o[ht][r];
    if (quad == 0) {
        ml_red[wave * 32 + l16]      = mx;
        ml_red[wave * 32 + 16 + l16] = lsum;
    }
    __syncthreads();

    // ---- 8-way cross-wave combine: thread -> (row=tid>>5, col0=(tid&31)*2) ----
    const int row = tid >> 5, c0 = (tid & 31) * 2;
    float M = -1e30f;
    #pragma unroll
    for (int w = 0; w < 8; w++) M = fmaxf(M, ml_red[w * 32 + row]);
    float wgt[8];
    float l = 0.f;
    #pragma unroll
    for (int w = 0; w < 8; w++) {
        wgt[w] = __expf(ml_red[w * 32 + row] - M);
        l += wgt[w] * ml_red[w * 32 + 16 + row];
    }
    const float inv = 1.0f / l;
    float* op = out + ((size_t)b * 2048 + q0 + row) * 64 + c0;
    #pragma unroll
    for (int i = 0; i < 2; i++) {
        const int col = c0 + i;
        float sv = 0.f;
        #pragma unroll
        for (int w = 0; w < 8; w++) sv += wgt[w] * o_red[(w * 16 + row) * 68 + col];
        op[i] = sv * inv;
    }
}

// ---------------------------------------------------------------------------
extern "C" void kernel_launch(void* const* d_in, const int* in_sizes, int n_in,
                              void* d_out, int out_size, void* d_ws, size_t ws_size,
                              hipStream_t stream) {
    const float* x  = (const float*)d_in[0];
    const float* Wq = (const float*)d_in[1];
    const float* Wk = (const float*)d_in[2];
    const float* Wv = (const float*)d_in[3];
    float* out = (float*)d_out;
    unsigned short* ws = (unsigned short*)d_ws;

    wtrans_kernel<<<dim3(48), 512, 0, stream>>>(Wq, Wk, Wv, ws + WT_OFF);
    proj_kernel<<<dim3(512), 512, 0, stream>>>(x, ws + WT_OFF - WT_OFF, ws); // x, wt via ws
    attn_kernel<<<dim3(512), 512, 0, stream>>>(ws, out);
}

// Round 12
// 124.484 us; speedup vs baseline: 3.0450x; 1.0129x over previous
//
#include <hip/hip_runtime.h>

// B=4, T=2048, C=1024, H=64. fp32 in/out, bf16 MFMA internally.
// wtrans -> proj (r7 shape, q pre-scaled 1/8) -> attn (32-row q-tiles,
// two-pass S^T softmax in 2 register-groups, alpha shuffled into o-row
// space at the merge — the r11 bug fix). XCD swizzle.
// ws layout (u16 elements):
//   [0,        524288)  q  bf16 (PRE-SCALED by 1/8)  [b*2048+t][64]
//   [524288,  1048576)  k  bf16  [b*2048+t][64]
//   [1048576, 1572864)  vT bf16  [b][h][t]   (b*131072 + h*2048 + t)
//   [1572864, 1769472)  wT bf16  [sel][h][c] (sel*65536 + h*1024 + c)

typedef __attribute__((ext_vector_type(8))) short short8;
typedef __attribute__((ext_vector_type(4))) float f32x4;

#define NTOT 524288   // 8192*64
#define WT_OFF (3 * NTOT)

__device__ __forceinline__ unsigned short f2bf(float f) {
    unsigned int u = __builtin_bit_cast(unsigned int, f);
    return (unsigned short)((u + 0x7fffu + ((u >> 16) & 1u)) >> 16);
}

__device__ __forceinline__ short8 pack8(float4 a, float4 b) {
    short8 r;
    r[0] = (short)f2bf(a.x); r[1] = (short)f2bf(a.y);
    r[2] = (short)f2bf(a.z); r[3] = (short)f2bf(a.w);
    r[4] = (short)f2bf(b.x); r[5] = (short)f2bf(b.y);
    r[6] = (short)f2bf(b.z); r[7] = (short)f2bf(b.w);
    return r;
}

// ---------------------------------------------------------------------------
// Kernel 1: W transpose (proven). 48 blocks x 512.
// ---------------------------------------------------------------------------
__global__ __launch_bounds__(512) void wtrans_kernel(
    const float* __restrict__ Wq, const float* __restrict__ Wk,
    const float* __restrict__ Wv, unsigned short* __restrict__ wt)
{
    __shared__ unsigned short tile[64 * 72];
    const int tid = threadIdx.x;
    const int sel = blockIdx.x % 3;
    const int c0  = (blockIdx.x / 3) * 64;
    const float* W = (sel == 0) ? Wq : ((sel == 1) ? Wk : Wv);
    {
        const int c  = tid >> 3;
        const int hg = (tid & 7) * 8;
        const float* src = W + (size_t)(c0 + c) * 64 + hg;
        #pragma unroll
        for (int i = 0; i < 8; i++) tile[c * 72 + hg + i] = f2bf(src[i]);
    }
    __syncthreads();
    {
        const int h  = tid >> 3;
        const int cg = (tid & 7) * 8;
        unsigned short* dst = wt + ((size_t)sel * 64 + h) * 1024 + c0 + cg;
        #pragma unroll
        for (int i = 0; i < 8; i++) dst[i] = tile[(cg + i) * 72 + h];
    }
}

// ---------------------------------------------------------------------------
// Kernel 2: fused projections — r7-proven shape (256 blocks x 512 thr,
// 32 t-rows/block, K-split-8, 3-stage LDS reduce) + exact 1/8 q-prescale.
// ---------------------------------------------------------------------------
__global__ __launch_bounds__(512) void proj_kernel(
    const float* __restrict__ x, const unsigned short* __restrict__ wt,
    unsigned short* __restrict__ ws)
{
    const int m0   = blockIdx.x * 32;
    const int tid  = threadIdx.x;
    const int wave = tid >> 6, lane = tid & 63;   // wave 0..7
    const int quad = lane >> 4, l16 = lane & 15;

    const unsigned short* wq = wt;
    const unsigned short* wk = wt + 65536;
    const unsigned short* wv = wt + 131072;

    // q/k stages: idx (w*32 + t)*66 + h   (8*32*66 = 16896)
    // v stage:    idx (w*64 + h)*33 + t   (8*64*33 = 16896)
    __shared__ float lds[16896];   // 67.6 KB

    f32x4 aq[2][4] = {}, ak[2][4] = {}, av[4][2] = {};

    const int kbase = wave * 128;
    const float* xrow0 = x + (size_t)(m0 + l16) * 1024 + kbase + quad * 8;
    const float* xrow1 = xrow0 + (size_t)16 * 1024;
    float4 xa0 = *(const float4*)(xrow0);
    float4 xb0 = *(const float4*)(xrow0 + 4);
    float4 xa1 = *(const float4*)(xrow1);
    float4 xb1 = *(const float4*)(xrow1 + 4);
    #pragma unroll
    for (int kk = 0; kk < 128; kk += 32) {
        const int nk = (kk + 32) & 127;     // wraps on last iter (unused)
        float4 na0 = *(const float4*)(xrow0 + nk);
        float4 nb0 = *(const float4*)(xrow0 + nk + 4);
        float4 na1 = *(const float4*)(xrow1 + nk);
        float4 nb1 = *(const float4*)(xrow1 + nk + 4);
        short8 af0 = pack8(xa0, xb0);
        short8 af1 = pack8(xa1, xb1);
        const int wo = kbase + kk + quad * 8;
        #pragma unroll
        for (int nt = 0; nt < 4; nt++) {
            const size_t ro = (size_t)(nt * 16 + l16) * 1024 + wo;
            short8 bq = *(const short8*)(wq + ro);
            short8 bk = *(const short8*)(wk + ro);
            short8 bv = *(const short8*)(wv + ro);
            aq[0][nt] = __builtin_amdgcn_mfma_f32_16x16x32_bf16(af0, bq, aq[0][nt], 0, 0, 0);
            aq[1][nt] = __builtin_amdgcn_mfma_f32_16x16x32_bf16(af1, bq, aq[1][nt], 0, 0, 0);
            ak[0][nt] = __builtin_amdgcn_mfma_f32_16x16x32_bf16(af0, bk, ak[0][nt], 0, 0, 0);
            ak[1][nt] = __builtin_amdgcn_mfma_f32_16x16x32_bf16(af1, bk, ak[1][nt], 0, 0, 0);
            av[nt][0] = __builtin_amdgcn_mfma_f32_16x16x32_bf16(bv, af0, av[nt][0], 0, 0, 0);
            av[nt][1] = __builtin_amdgcn_mfma_f32_16x16x32_bf16(bv, af1, av[nt][1], 0, 0, 0);
        }
        xa0 = na0; xb0 = nb0; xa1 = na1; xb1 = nb1;
    }

    const int b   = m0 >> 11;
    const int tb0 = m0 & 2047;
    const int rrow = tid >> 4, rh0 = (tid & 15) * 4;   // q/k reduce mapping

    // ---- stage Q (store pre-scaled by 1/8: exact) ----
    #pragma unroll
    for (int tf = 0; tf < 2; tf++)
        #pragma unroll
        for (int nt = 0; nt < 4; nt++)
            #pragma unroll
            for (int r = 0; r < 4; r++)
                lds[(wave * 32 + tf * 16 + quad * 4 + r) * 66 + nt * 16 + l16]
                    = aq[tf][nt][r];
    __syncthreads();
    {
        float s[4] = {0.f, 0.f, 0.f, 0.f};
        #pragma unroll
        for (int w = 0; w < 8; w++)
            #pragma unroll
            for (int i = 0; i < 4; i++)
                s[i] += lds[(w * 32 + rrow) * 66 + rh0 + i];
        #pragma unroll
        for (int i = 0; i < 4; i++)
            ws[(size_t)(m0 + rrow) * 64 + rh0 + i] = f2bf(s[i] * 0.125f);
    }
    __syncthreads();
    // ---- stage K ----
    #pragma unroll
    for (int tf = 0; tf < 2; tf++)
        #pragma unroll
        for (int nt = 0; nt < 4; nt++)
            #pragma unroll
            for (int r = 0; r < 4; r++)
                lds[(wave * 32 + tf * 16 + quad * 4 + r) * 66 + nt * 16 + l16]
                    = ak[tf][nt][r];
    __syncthreads();
    {
        float s[4] = {0.f, 0.f, 0.f, 0.f};
        #pragma unroll
        for (int w = 0; w < 8; w++)
            #pragma unroll
            for (int i = 0; i < 4; i++)
                s[i] += lds[(w * 32 + rrow) * 66 + rh0 + i];
        #pragma unroll
        for (int i = 0; i < 4; i++)
            ws[NTOT + (size_t)(m0 + rrow) * 64 + rh0 + i] = f2bf(s[i]);
    }
    __syncthreads();
    // ---- stage V: av[nt][tf][r] -> h = nt*16+quad*4+r, t = tf*16+l16 ----
    #pragma unroll
    for (int nt = 0; nt < 4; nt++)
        #pragma unroll
        for (int tf = 0; tf < 2; tf++)
            #pragma unroll
            for (int r = 0; r < 4; r++)
                lds[(wave * 64 + nt * 16 + quad * 4 + r) * 33 + tf * 16 + l16]
                    = av[nt][tf][r];
    __syncthreads();
    {
        const int h = tid >> 3, t0 = (tid & 7) * 4;
        unsigned short* vdst = ws + 2 * NTOT + (size_t)b * 131072
                             + (size_t)h * 2048 + tb0;
        float s[4] = {0.f, 0.f, 0.f, 0.f};
        #pragma unroll
        for (int w = 0; w < 8; w++)
            #pragma unroll
            for (int i = 0; i < 4; i++)
                s[i] += lds[(w * 64 + h) * 33 + t0 + i];
        #pragma unroll
        for (int i = 0; i < 4; i++)
            vdst[t0 + i] = f2bf(s[i]);
    }
}

// ---------------------------------------------------------------------------
// Kernel 3: flash attention, 32-row q-tiles, 256 blocks x 512 thr (8 waves).
// wave = (qs = wave&1 -> q-subtile, ks = wave>>1 -> k-split). Wave owns
// tiles t = ks + 4*ti + 16*g, two register-groups of <=4 with one online
// merge. Two-pass S^T softmax per group (r10-proven core).
// MERGE FIX: alpha lives in q=l16 space; o rows are q=quad*4+r — shuffle
// alpha across the 16-lane segment before rescaling O (alpha is
// quad-uniform after the cross-quad max reduce, so this is exact).
// ---------------------------------------------------------------------------
__global__ __launch_bounds__(512, 2) void attn_kernel(
    const unsigned short* __restrict__ ws, float* __restrict__ out)
{
    __shared__ unsigned short p_lds[8 * 16 * 72];   // 18.4 KB
    __shared__ float o_red[8 * 16 * 68];            // 34.8 KB
    __shared__ float ml_red[8 * 32];                // 1 KB
    const int tid = threadIdx.x;
    const int bid = blockIdx.x;
    const int wave = tid >> 6, lane = tid & 63;
    const int quad = lane >> 4, l16 = lane & 15;

    const int xcd  = bid & 7;
    const int slot = bid >> 3;
    const int b    = xcd & 3;
    const int qt32 = (slot << 1) | (xcd >> 2);   // 0..63
    const int q0   = qt32 * 32;
    const int qs   = wave & 1;                   // q-subtile
    const int ks   = wave >> 1;                  // k-split lane (0..3)

    const unsigned short* Q  = ws + (size_t)b * 131072;
    const unsigned short* K  = ws + NTOT + (size_t)b * 131072;
    const unsigned short* VT = ws + 2 * NTOT + (size_t)b * 131072;

    // Q fragments (B-operand): B[k=c][n=l16] = Q[q0+qs*16+l16][c]
    const int qrow = q0 + qs * 16 + l16;
    short8 qf0 = *(const short8*)(Q + (size_t)qrow * 64 + quad * 8);
    short8 qf1 = *(const short8*)(Q + (size_t)qrow * 64 + 32 + quad * 8);

    const int nkt = (qt32 >> 1) + 1;    // 64-wide k-tiles for this q-tile
    const int qi  = qrow;               // this lane's q row (S^T mask)

    float m = -1e30f, lsum = 0.f;
    f32x4 o[4] = {};

    #pragma unroll
    for (int g = 0; g < 2; g++) {
        if (ks + 16 * g >= nkt) break;   // wave-uniform
        // ---- pass A: S^T for up to 4 tiles of this group ----
        f32x4 st[4][4] = {};
        #pragma unroll
        for (int ti = 0; ti < 4; ti++) {
            const int t = ks + 4 * ti + 16 * g;
            if (t < nkt) {
                const int j0 = t * 64;
                #pragma unroll
                for (int nt = 0; nt < 4; nt++) {
                    const unsigned short* kp = K + (size_t)(j0 + nt * 16 + l16) * 64 + quad * 8;
                    short8 kf0 = *(const short8*)(kp);
                    short8 kf1 = *(const short8*)(kp + 32);
                    st[ti][nt] = __builtin_amdgcn_mfma_f32_16x16x32_bf16(kf0, qf0, st[ti][nt], 0, 0, 0);
                    st[ti][nt] = __builtin_amdgcn_mfma_f32_16x16x32_bf16(kf1, qf1, st[ti][nt], 0, 0, 0);
                }
            }
        }
        // ---- mask (causal + ==0 quirk; scale pre-folded) + in-reg max ----
        float gm = -1e30f;
        #pragma unroll
        for (int ti = 0; ti < 4; ti++) {
            const int t = ks + 4 * ti + 16 * g;
            if (t < nkt) {
                const int j0 = t * 64;
                #pragma unroll
                for (int nt = 0; nt < 4; nt++) {
                    const int kb = j0 + nt * 16 + quad * 4;
                    #pragma unroll
                    for (int r = 0; r < 4; r++) {
                        float v = st[ti][nt][r];
                        v = (kb + r > qi || v == 0.0f) ? -1e30f : v;
                        st[ti][nt][r] = v;
                        gm = fmaxf(gm, v);
                    }
                }
            }
        }
        gm = fmaxf(gm, __shfl_xor(gm, 16));
        gm = fmaxf(gm, __shfl_xor(gm, 32));   // gm now quad-uniform, per q=l16
        const float mnew = fmaxf(m, gm);
        const float alpha = __expf(m - mnew); // keyed to q = l16
        lsum *= alpha;                        // lsum keyed to q = l16: OK
        // o rows are q = quad*4+r -> fetch matching alphas via shuffle
        {
            float a_r[4];
            #pragma unroll
            for (int r = 0; r < 4; r++)
                a_r[r] = __shfl(alpha, quad * 4 + r, 16);
            #pragma unroll
            for (int ht = 0; ht < 4; ht++)
                #pragma unroll
                for (int r = 0; r < 4; r++)
                    o[ht][r] *= a_r[r];
        }
        m = mnew;
        // ---- pass B: exp, P->LDS, O += P.V^T ----
        #pragma unroll
        for (int ti = 0; ti < 4; ti++) {
            const int t = ks + 4 * ti + 16 * g;
            if (t < nkt) {
                const int j0 = t * 64;
                #pragma unroll
                for (int nt = 0; nt < 4; nt++)
                    #pragma unroll
                    for (int r = 0; r < 4; r++) {
                        float p = __expf(st[ti][nt][r] - m);
                        lsum += p;
                        p_lds[(wave * 16 + l16) * 72 + nt * 16 + quad * 4 + r] = f2bf(p);
                    }
                #pragma unroll
                for (int kc = 0; kc < 2; kc++) {
                    short8 pf = *(const short8*)&p_lds[(wave * 16 + l16) * 72 + kc * 32 + quad * 8];
                    #pragma unroll
                    for (int ht = 0; ht < 4; ht++) {
                        short8 vf = *(const short8*)(VT + (size_t)(ht * 16 + l16) * 2048 + j0 + kc * 32 + quad * 8);
                        o[ht] = __builtin_amdgcn_mfma_f32_16x16x32_bf16(pf, vf, o[ht], 0, 0, 0);
                    }
                }
            }
        }
    }
    lsum += __shfl_xor(lsum, 16);
    lsum += __shfl_xor(lsum, 32);

    // ---- stash per-wave partials (O rows q=quad*4+r; m/l rows q=l16) ----
    #pragma unroll
    for (int ht = 0; ht < 4; ht++)
        #pragma unroll
        for (int r = 0; r < 4; r++)
            o_red[(wave * 16 + quad * 4 + r) * 68 + ht * 16 + l16] = o[ht][r];
    if (quad == 0) {
        ml_red[wave * 32 + l16]      = m;
        ml_red[wave * 32 + 16 + l16] = lsum;
    }
    __syncthreads();

    // ---- 4-way combine per q-subtile: thread -> (row=tid>>4, col0=(tid&15)*4) ----
    const int row = tid >> 4;           // 0..31
    const int c0  = (tid & 15) * 4;
    const int qs2 = row >> 4, lr = row & 15;
    float M = -1e30f;
    #pragma unroll
    for (int k = 0; k < 4; k++) M = fmaxf(M, ml_red[(qs2 + 2 * k) * 32 + lr]);
    float wgt[4];
    float l = 0.f;
    #pragma unroll
    for (int k = 0; k < 4; k++) {
        wgt[k] = __expf(ml_red[(qs2 + 2 * k) * 32 + lr] - M);
        l += wgt[k] * ml_red[(qs2 + 2 * k) * 32 + 16 + lr];
    }
    const float inv = 1.0f / l;
    float* op = out + ((size_t)b * 2048 + q0 + row) * 64 + c0;
    #pragma unroll
    for (int i = 0; i < 4; i++) {
        const int col = c0 + i;
        float sv = 0.f;
        #pragma unroll
        for (int k = 0; k < 4; k++)
            sv += wgt[k] * o_red[(((qs2 + 2 * k) * 16) + lr) * 68 + col];
        op[i] = sv * inv;
    }
}

// ---------------------------------------------------------------------------
extern "C" void kernel_launch(void* const* d_in, const int* in_sizes, int n_in,
                              void* d_out, int out_size, void* d_ws, size_t ws_size,
                              hipStream_t stream) {
    const float* x  = (const float*)d_in[0];
    const float* Wq = (const float*)d_in[1];
    const float* Wk = (const float*)d_in[2];
    const float* Wv = (const float*)d_in[3];
    float* out = (float*)d_out;
    unsigned short* ws = (unsigned short*)d_ws;

    wtrans_kernel<<<dim3(48), 512, 0, stream>>>(Wq, Wk, Wv, ws + WT_OFF);
    proj_kernel<<<dim3(256), 512, 0, stream>>>(x, ws + WT_OFF, ws);
    attn_kernel<<<dim3(256), 512, 0, stream>>>(ws, out);
}